// Round 1
// baseline (1645.745 us; speedup 1.0000x reference)
//
#include <hip/hip_runtime.h>
#include <hip/hip_bf16.h>

#define N_NODES 100000
#define M_EDGES 1600000
#define DIM 128

// ---------------------------------------------------------------------------
// degree histogram: deg[i] = #edges with e0 == i
// ---------------------------------------------------------------------------
__global__ __launch_bounds__(256) void deg_hist(const int* __restrict__ e0,
                                                int* __restrict__ deg) {
    const int stride = gridDim.x * blockDim.x;
    for (int i = blockIdx.x * blockDim.x + threadIdx.x; i < M_EDGES; i += stride)
        atomicAdd(&deg[e0[i]], 1);
}

// ---------------------------------------------------------------------------
// single-block exclusive scan of deg -> row_ptr (N+1) and cursor copy
// ---------------------------------------------------------------------------
__global__ __launch_bounds__(1024) void scan_kernel(const int* __restrict__ deg,
                                                    int* __restrict__ row_ptr,
                                                    int* __restrict__ cursor) {
    __shared__ int woff[16];
    __shared__ int s_carry;
    const int tid  = threadIdx.x;
    const int lane = tid & 63;
    const int wid  = tid >> 6;
    if (tid == 0) s_carry = 0;
    __syncthreads();
    for (int base = 0; base < N_NODES; base += 1024) {
        const int i   = base + tid;
        const int val = (i < N_NODES) ? deg[i] : 0;
        int incl = val;
        #pragma unroll
        for (int off = 1; off < 64; off <<= 1) {
            int t = __shfl_up(incl, off, 64);
            if (lane >= off) incl += t;
        }
        if (lane == 63) woff[wid] = incl;
        __syncthreads();
        if (wid == 0) {
            int w = (lane < 16) ? woff[lane] : 0;
            int winc = w;
            #pragma unroll
            for (int off = 1; off < 16; off <<= 1) {
                int t = __shfl_up(winc, off, 64);
                if (lane >= off) winc += t;
            }
            if (lane < 16) woff[lane] = winc - w;   // exclusive wave offsets
        }
        __syncthreads();
        const int carry = s_carry;
        const int excl  = carry + woff[wid] + (incl - val);
        if (i < N_NODES) { row_ptr[i] = excl; cursor[i] = excl; }
        __syncthreads();
        if (tid == 1023) s_carry = carry + woff[15] + incl;  // block total
        __syncthreads();
    }
    if (tid == 0) row_ptr[N_NODES] = s_carry;   // == M_EDGES
}

// ---------------------------------------------------------------------------
// CSR fill: group src (e1) by dst (e0)
// ---------------------------------------------------------------------------
__global__ __launch_bounds__(256) void csr_fill(const int* __restrict__ e0,
                                                const int* __restrict__ e1,
                                                int* __restrict__ cursor,
                                                int* __restrict__ csr) {
    const int stride = gridDim.x * blockDim.x;
    for (int i = blockIdx.x * blockDim.x + threadIdx.x; i < M_EDGES; i += stride) {
        const int pos = atomicAdd(&cursor[e0[i]], 1);
        csr[pos] = e1[i];
    }
}

// ---------------------------------------------------------------------------
// Y = X @ W,  X: (N,128) fp32, W: (128,128) fp32.  64x64 tile, 4x4 micro.
// ---------------------------------------------------------------------------
#define GR 64
#define GC 64
__global__ __launch_bounds__(256) void gemm_xw(const float* __restrict__ X,
                                               const float* __restrict__ W,
                                               float* __restrict__ Y) {
    __shared__ float  xs[GR][DIM + 4];       // row-major x tile, pad 4 floats
    __shared__ float4 wt4[GC][DIM / 4];      // W^T, XOR-swizzled chunks
    const int row0 = blockIdx.x * GR;
    const int col0 = blockIdx.y * GC;
    const int tid  = threadIdx.x;

    // stage x rows (coalesced float4)
    #pragma unroll
    for (int i = tid; i < GR * (DIM / 4); i += 256) {
        const int r = i / (DIM / 4);
        const int k = (i % (DIM / 4)) * 4;
        const int row = row0 + r;
        float4 t = make_float4(0.f, 0.f, 0.f, 0.f);
        if (row < N_NODES) t = *(const float4*)&X[(size_t)row * DIM + k];
        *(float4*)&xs[r][k] = t;
    }
    // stage W transposed with chunk swizzle: chunk p stored at p ^ ((c>>2)&7)
    #pragma unroll
    for (int i = tid; i < DIM * (GC / 4); i += 256) {
        const int k = i / (GC / 4);          // 0..127
        const int c = (i % (GC / 4)) * 4;    // 0,4,..,60
        const float4 t = *(const float4*)&W[k * DIM + col0 + c];
        const int k4 = k >> 2, kr = k & 3;
        const int swz = (c >> 2) & 7;        // same for c..c+3
        ((float*)&wt4[c + 0][k4 ^ swz])[kr] = t.x;
        ((float*)&wt4[c + 1][k4 ^ swz])[kr] = t.y;
        ((float*)&wt4[c + 2][k4 ^ swz])[kr] = t.z;
        ((float*)&wt4[c + 3][k4 ^ swz])[kr] = t.w;
    }
    __syncthreads();

    const int tr = (tid >> 4) << 2;   // micro-tile row base
    const int tc = (tid & 15) << 2;   // micro-tile col base
    const int swzb = (tc >> 2) & 7;
    float acc[4][4];
    #pragma unroll
    for (int i = 0; i < 4; ++i)
        #pragma unroll
        for (int j = 0; j < 4; ++j) acc[i][j] = 0.f;

    #pragma unroll 2
    for (int kc = 0; kc < DIM; kc += 4) {
        const int k4 = kc >> 2;
        float4 a[4], b[4];
        #pragma unroll
        for (int i = 0; i < 4; ++i) a[i] = *(const float4*)&xs[tr + i][kc];
        #pragma unroll
        for (int j = 0; j < 4; ++j) b[j] = wt4[tc + j][k4 ^ swzb];
        #pragma unroll
        for (int i = 0; i < 4; ++i)
            #pragma unroll
            for (int j = 0; j < 4; ++j)
                acc[i][j] += a[i].x * b[j].x + a[i].y * b[j].y +
                             a[i].z * b[j].z + a[i].w * b[j].w;
    }

    #pragma unroll
    for (int i = 0; i < 4; ++i) {
        const int row = row0 + tr + i;
        if (row < N_NODES) {
            float4 o = make_float4(acc[i][0], acc[i][1], acc[i][2], acc[i][3]);
            *(float4*)&Y[(size_t)row * DIM + col0 + tc] = o;
        }
    }
}

// ---------------------------------------------------------------------------
// z1 = 0.1 * v   (first PPR step from z0 = 0)
// ---------------------------------------------------------------------------
__global__ __launch_bounds__(256) void ppr_init(const float* __restrict__ v,
                                                float* __restrict__ z) {
    const int total  = N_NODES * DIM / 4;
    const int stride = gridDim.x * blockDim.x;
    for (int i = blockIdx.x * blockDim.x + threadIdx.x; i < total; i += stride) {
        float4 t = ((const float4*)v)[i];
        t.x *= 0.1f; t.y *= 0.1f; t.z *= 0.1f; t.w *= 0.1f;
        ((float4*)z)[i] = t;
    }
}

// ---------------------------------------------------------------------------
// one PPR step: zout[i] = 0.9 * (1/deg_i) * sum_{j in nbr(i)} zin[j] + 0.1*v[i]
// one wave per node, lane holds 2 features (float2 -> 512B coalesced gather)
// ---------------------------------------------------------------------------
__global__ __launch_bounds__(256) void spmv_step(const int* __restrict__ row_ptr,
                                                 const int* __restrict__ csr,
                                                 const float* __restrict__ zin,
                                                 const float* __restrict__ v,
                                                 float* __restrict__ zout) {
    const int node = blockIdx.x * 4 + (threadIdx.x >> 6);
    if (node >= N_NODES) return;
    const int lane  = threadIdx.x & 63;
    const int start = row_ptr[node];
    const int end   = row_ptr[node + 1];
    float ax0 = 0.f, ay0 = 0.f, ax1 = 0.f, ay1 = 0.f;
    int j = start;
    for (; j + 2 <= end; j += 2) {                    // 2 independent chains
        const int s0 = csr[j];
        const int s1 = csr[j + 1];
        const float2 t0 = *(const float2*)&zin[(size_t)s0 * DIM + lane * 2];
        const float2 t1 = *(const float2*)&zin[(size_t)s1 * DIM + lane * 2];
        ax0 += t0.x; ay0 += t0.y;
        ax1 += t1.x; ay1 += t1.y;
    }
    if (j < end) {
        const int s0 = csr[j];
        const float2 t0 = *(const float2*)&zin[(size_t)s0 * DIM + lane * 2];
        ax0 += t0.x; ay0 += t0.y;
    }
    const float invd = 1.0f / ((float)(end - start) + 1e-16f);
    const float2 vv = *(const float2*)&v[(size_t)node * DIM + lane * 2];
    float2 o;
    o.x = 0.9f * (ax0 + ax1) * invd + 0.1f * vv.x;
    o.y = 0.9f * (ay0 + ay1) * invd + 0.1f * vv.y;
    *(float2*)&zout[(size_t)node * DIM + lane * 2] = o;
}

// ---------------------------------------------------------------------------
// out = LayerNorm(z + skip + lin_b) * ln_g + ln_b    (wave per row)
// ---------------------------------------------------------------------------
__global__ __launch_bounds__(256) void final_ln(const float* __restrict__ z,
                                                const float* __restrict__ skip,
                                                const float* __restrict__ lin_b,
                                                const float* __restrict__ ln_g,
                                                const float* __restrict__ ln_b,
                                                float* __restrict__ out) {
    const int node = blockIdx.x * 4 + (threadIdx.x >> 6);
    if (node >= N_NODES) return;
    const int lane = threadIdx.x & 63;
    const size_t base = (size_t)node * DIM + lane * 2;
    float2 t = *(const float2*)&z[base];
    const float2 sk = *(const float2*)&skip[base];
    const float2 lb = *(const float2*)&lin_b[lane * 2];
    t.x += sk.x + lb.x;
    t.y += sk.y + lb.y;
    float s = t.x + t.y;
    float q = t.x * t.x + t.y * t.y;
    #pragma unroll
    for (int off = 32; off; off >>= 1) {
        s += __shfl_xor(s, off, 64);
        q += __shfl_xor(q, off, 64);
    }
    const float mu   = s * (1.0f / 128.0f);
    const float var  = q * (1.0f / 128.0f) - mu * mu;
    const float rstd = rsqrtf(var + 1e-5f);
    const float2 g = *(const float2*)&ln_g[lane * 2];
    const float2 b = *(const float2*)&ln_b[lane * 2];
    float2 o;
    o.x = (t.x - mu) * rstd * g.x + b.x;
    o.y = (t.y - mu) * rstd * g.y + b.y;
    *(float2*)&out[base] = o;
}

// ---------------------------------------------------------------------------
extern "C" void kernel_launch(void* const* d_in, const int* in_sizes, int n_in,
                              void* d_out, int out_size, void* d_ws, size_t ws_size,
                              hipStream_t stream) {
    const float* x      = (const float*)d_in[0];
    const int*   e      = (const int*)d_in[1];
    const float* lin_w  = (const float*)d_in[2];
    const float* lin_b  = (const float*)d_in[3];
    const float* skip_w = (const float*)d_in[4];
    const float* ln_g   = (const float*)d_in[5];
    const float* ln_b   = (const float*)d_in[6];
    float* out = (float*)d_out;

    const int* e0 = e;
    const int* e1 = e + M_EDGES;

    // workspace layout
    char* ws = (char*)d_ws;
    const size_t fsz = (size_t)N_NODES * DIM * sizeof(float);   // 51.2 MB
    float* v  = (float*)(ws);
    float* zA = (float*)(ws + fsz);
    float* zB = (float*)(ws + 2 * fsz);
    int* deg     = (int*)(ws + 3 * fsz);
    int* row_ptr = deg + N_NODES;
    int* cursor  = row_ptr + (N_NODES + 1);
    int* csr     = cursor + N_NODES;

    hipMemsetAsync(deg, 0, N_NODES * sizeof(int), stream);
    deg_hist<<<2048, 256, 0, stream>>>(e0, deg);
    scan_kernel<<<1, 1024, 0, stream>>>(deg, row_ptr, cursor);
    csr_fill<<<2048, 256, 0, stream>>>(e0, e1, cursor, csr);

    // v = x @ lin_w
    gemm_xw<<<dim3((N_NODES + GR - 1) / GR, DIM / GC), 256, 0, stream>>>(x, lin_w, v);

    // PPR power iteration: z1 = 0.1*v ; then 9 more steps (ITERS=10 total)
    ppr_init<<<2048, 256, 0, stream>>>(v, zA);
    for (int it = 0; it < 9; ++it) {
        const float* zi = (it & 1) ? zB : zA;
        float*       zo = (it & 1) ? zA : zB;
        spmv_step<<<N_NODES / 4, 256, 0, stream>>>(row_ptr, csr, zi, v, zo);
    }
    // final z is in zB (9 steps: A->B,B->A,...,A->B)

    // skip = x @ skip_w  (reuse zA)
    gemm_xw<<<dim3((N_NODES + GR - 1) / GR, DIM / GC), 256, 0, stream>>>(x, skip_w, zA);

    // out = LN(zB + zA + lin_b)
    final_ln<<<N_NODES / 4, 256, 0, stream>>>(zB, zA, lin_b, ln_g, ln_b, out);
}

// Round 2
// 1131.263 us; speedup vs baseline: 1.4548x; 1.4548x over previous
//
#include <hip/hip_runtime.h>
#include <hip/hip_bf16.h>

#define N_NODES 100000
#define M_EDGES 1600000
#define DIM 128
#define NBLK_SCAN ((N_NODES + 1023) / 1024)   // 98

typedef unsigned int uint32;

// round-to-nearest-even pack of two fp32 -> two bf16 in one uint32
__device__ __forceinline__ uint32 pack_bf16(float a, float b) {
    uint32 ua = __float_as_uint(a);
    uint32 ub = __float_as_uint(b);
    ua += 0x7fffu + ((ua >> 16) & 1u);
    ub += 0x7fffu + ((ub >> 16) & 1u);
    return (ua >> 16) | (ub & 0xffff0000u);
}

__device__ __forceinline__ float2 unpack_bf16(uint32 u) {
    float2 r;
    r.x = __uint_as_float(u << 16);
    r.y = __uint_as_float(u & 0xffff0000u);
    return r;
}

// ---------------------------------------------------------------------------
// degree histogram
// ---------------------------------------------------------------------------
__global__ __launch_bounds__(256) void deg_hist(const int* __restrict__ e0,
                                                int* __restrict__ deg) {
    const int stride = gridDim.x * blockDim.x;
    for (int i = blockIdx.x * blockDim.x + threadIdx.x; i < M_EDGES; i += stride)
        atomicAdd(&deg[e0[i]], 1);
}

// ---------------------------------------------------------------------------
// hierarchical scan, phase 1: per-block exclusive scan + block totals
// ---------------------------------------------------------------------------
__global__ __launch_bounds__(1024) void scan_blocks(const int* __restrict__ deg,
                                                    int* __restrict__ row_ptr,
                                                    int* __restrict__ blk_sums) {
    __shared__ int woff[16];
    const int tid  = threadIdx.x;
    const int lane = tid & 63;
    const int wid  = tid >> 6;
    const int i    = blockIdx.x * 1024 + tid;
    const int val  = (i < N_NODES) ? deg[i] : 0;
    int incl = val;
    #pragma unroll
    for (int off = 1; off < 64; off <<= 1) {
        int t = __shfl_up(incl, off, 64);
        if (lane >= off) incl += t;
    }
    if (lane == 63) woff[wid] = incl;
    __syncthreads();
    if (wid == 0) {
        int w = (lane < 16) ? woff[lane] : 0;
        int winc = w;
        #pragma unroll
        for (int off = 1; off < 16; off <<= 1) {
            int t = __shfl_up(winc, off, 64);
            if (lane >= off) winc += t;
        }
        if (lane < 16) woff[lane] = winc - w;    // exclusive wave offsets
    }
    __syncthreads();
    if (i < N_NODES) row_ptr[i] = woff[wid] + incl - val;   // block-local excl
    if (tid == 1023) blk_sums[blockIdx.x] = woff[15] + incl; // block total
}

// ---------------------------------------------------------------------------
// phase 2: exclusive scan of the 98 block totals (single small block)
// ---------------------------------------------------------------------------
__global__ __launch_bounds__(128) void scan_tops(int* __restrict__ blk_sums) {
    __shared__ int tot0;
    const int tid  = threadIdx.x;
    const int lane = tid & 63;
    const int wid  = tid >> 6;
    const int val  = (tid < NBLK_SCAN) ? blk_sums[tid] : 0;
    int incl = val;
    #pragma unroll
    for (int off = 1; off < 64; off <<= 1) {
        int t = __shfl_up(incl, off, 64);
        if (lane >= off) incl += t;
    }
    if (tid == 63) tot0 = incl;
    __syncthreads();
    const int excl = incl - val + (wid ? tot0 : 0);
    if (tid < NBLK_SCAN) blk_sums[tid] = excl;
}

// ---------------------------------------------------------------------------
// phase 3: add block offsets, produce row_ptr + cursor
// ---------------------------------------------------------------------------
__global__ __launch_bounds__(1024) void scan_add(const int* __restrict__ blk_sums,
                                                 int* __restrict__ row_ptr,
                                                 int* __restrict__ cursor) {
    const int i = blockIdx.x * 1024 + threadIdx.x;
    if (i < N_NODES) {
        const int r = row_ptr[i] + blk_sums[blockIdx.x];
        row_ptr[i] = r;
        cursor[i]  = r;
    }
    if (i == 0) row_ptr[N_NODES] = M_EDGES;
}

// ---------------------------------------------------------------------------
// CSR fill
// ---------------------------------------------------------------------------
__global__ __launch_bounds__(256) void csr_fill(const int* __restrict__ e0,
                                                const int* __restrict__ e1,
                                                int* __restrict__ cursor,
                                                int* __restrict__ csr) {
    const int stride = gridDim.x * blockDim.x;
    for (int i = blockIdx.x * blockDim.x + threadIdx.x; i < M_EDGES; i += stride) {
        const int pos = atomicAdd(&cursor[e0[i]], 1);
        csr[pos] = e1[i];
    }
}

// ---------------------------------------------------------------------------
// Y = X @ W,  fp32 vector GEMM (64x64 tile, 4x4 micro)
// ---------------------------------------------------------------------------
#define GR 64
#define GC 64
__global__ __launch_bounds__(256) void gemm_xw(const float* __restrict__ X,
                                               const float* __restrict__ W,
                                               float* __restrict__ Y) {
    __shared__ float  xs[GR][DIM + 4];
    __shared__ float4 wt4[GC][DIM / 4];
    const int row0 = blockIdx.x * GR;
    const int col0 = blockIdx.y * GC;
    const int tid  = threadIdx.x;

    #pragma unroll
    for (int i = tid; i < GR * (DIM / 4); i += 256) {
        const int r = i / (DIM / 4);
        const int k = (i % (DIM / 4)) * 4;
        const int row = row0 + r;
        float4 t = make_float4(0.f, 0.f, 0.f, 0.f);
        if (row < N_NODES) t = *(const float4*)&X[(size_t)row * DIM + k];
        *(float4*)&xs[r][k] = t;
    }
    #pragma unroll
    for (int i = tid; i < DIM * (GC / 4); i += 256) {
        const int k = i / (GC / 4);
        const int c = (i % (GC / 4)) * 4;
        const float4 t = *(const float4*)&W[k * DIM + col0 + c];
        const int k4 = k >> 2, kr = k & 3;
        const int swz = (c >> 2) & 7;
        ((float*)&wt4[c + 0][k4 ^ swz])[kr] = t.x;
        ((float*)&wt4[c + 1][k4 ^ swz])[kr] = t.y;
        ((float*)&wt4[c + 2][k4 ^ swz])[kr] = t.z;
        ((float*)&wt4[c + 3][k4 ^ swz])[kr] = t.w;
    }
    __syncthreads();

    const int tr = (tid >> 4) << 2;
    const int tc = (tid & 15) << 2;
    const int swzb = (tc >> 2) & 7;
    float acc[4][4];
    #pragma unroll
    for (int i = 0; i < 4; ++i)
        #pragma unroll
        for (int j = 0; j < 4; ++j) acc[i][j] = 0.f;

    #pragma unroll 2
    for (int kc = 0; kc < DIM; kc += 4) {
        const int k4 = kc >> 2;
        float4 a[4], b[4];
        #pragma unroll
        for (int i = 0; i < 4; ++i) a[i] = *(const float4*)&xs[tr + i][kc];
        #pragma unroll
        for (int j = 0; j < 4; ++j) b[j] = wt4[tc + j][k4 ^ swzb];
        #pragma unroll
        for (int i = 0; i < 4; ++i)
            #pragma unroll
            for (int j = 0; j < 4; ++j)
                acc[i][j] += a[i].x * b[j].x + a[i].y * b[j].y +
                             a[i].z * b[j].z + a[i].w * b[j].w;
    }

    #pragma unroll
    for (int i = 0; i < 4; ++i) {
        const int row = row0 + tr + i;
        if (row < N_NODES) {
            float4 o = make_float4(acc[i][0], acc[i][1], acc[i][2], acc[i][3]);
            *(float4*)&Y[(size_t)row * DIM + col0 + tc] = o;
        }
    }
}

// ---------------------------------------------------------------------------
// z1 = 0.1 * v, packed to bf16
// ---------------------------------------------------------------------------
__global__ __launch_bounds__(256) void ppr_init_bf16(const float* __restrict__ v,
                                                     uint32* __restrict__ z) {
    const int total  = N_NODES * (DIM / 2);
    const int stride = gridDim.x * blockDim.x;
    for (int i = blockIdx.x * blockDim.x + threadIdx.x; i < total; i += stride) {
        const float2 t = *(const float2*)&v[(size_t)i * 2];
        z[i] = pack_bf16(0.1f * t.x, 0.1f * t.y);
    }
}

// ---------------------------------------------------------------------------
// one PPR step on bf16 z: zout = pack(0.9*invd*sum(nbr) + 0.1*v)
// wave per node, lane holds 2 features (one uint32 -> 256B coalesced row)
// ---------------------------------------------------------------------------
__global__ __launch_bounds__(256) void spmv_bf16(const int* __restrict__ row_ptr,
                                                 const int* __restrict__ csr,
                                                 const uint32* __restrict__ zin,
                                                 const float* __restrict__ v,
                                                 uint32* __restrict__ zout) {
    const int node = blockIdx.x * 4 + (threadIdx.x >> 6);
    if (node >= N_NODES) return;
    const int lane  = threadIdx.x & 63;
    const int start = row_ptr[node];
    const int end   = row_ptr[node + 1];
    float ax0 = 0.f, ay0 = 0.f, ax1 = 0.f, ay1 = 0.f;
    float ax2 = 0.f, ay2 = 0.f, ax3 = 0.f, ay3 = 0.f;
    int j = start;
    for (; j + 4 <= end; j += 4) {
        const int s0 = csr[j], s1 = csr[j + 1], s2 = csr[j + 2], s3 = csr[j + 3];
        const float2 t0 = unpack_bf16(zin[(size_t)s0 * 64 + lane]);
        const float2 t1 = unpack_bf16(zin[(size_t)s1 * 64 + lane]);
        const float2 t2 = unpack_bf16(zin[(size_t)s2 * 64 + lane]);
        const float2 t3 = unpack_bf16(zin[(size_t)s3 * 64 + lane]);
        ax0 += t0.x; ay0 += t0.y;
        ax1 += t1.x; ay1 += t1.y;
        ax2 += t2.x; ay2 += t2.y;
        ax3 += t3.x; ay3 += t3.y;
    }
    for (; j < end; ++j) {
        const float2 t0 = unpack_bf16(zin[(size_t)csr[j] * 64 + lane]);
        ax0 += t0.x; ay0 += t0.y;
    }
    const float invd = 1.0f / ((float)(end - start) + 1e-16f);
    const float2 vv = *(const float2*)&v[(size_t)node * DIM + lane * 2];
    const float ox = 0.9f * ((ax0 + ax1) + (ax2 + ax3)) * invd + 0.1f * vv.x;
    const float oy = 0.9f * ((ay0 + ay1) + (ay2 + ay3)) * invd + 0.1f * vv.y;
    zout[(size_t)node * 64 + lane] = pack_bf16(ox, oy);
}

// ---------------------------------------------------------------------------
// final PPR step fused with skip + bias + LayerNorm, fp32 out
// ---------------------------------------------------------------------------
__global__ __launch_bounds__(256) void spmv_final_ln(const int* __restrict__ row_ptr,
                                                     const int* __restrict__ csr,
                                                     const uint32* __restrict__ zin,
                                                     const float* __restrict__ v,
                                                     const float* __restrict__ skip,
                                                     const float* __restrict__ lin_b,
                                                     const float* __restrict__ ln_g,
                                                     const float* __restrict__ ln_b,
                                                     float* __restrict__ out) {
    const int node = blockIdx.x * 4 + (threadIdx.x >> 6);
    if (node >= N_NODES) return;
    const int lane  = threadIdx.x & 63;
    const int start = row_ptr[node];
    const int end   = row_ptr[node + 1];
    float ax0 = 0.f, ay0 = 0.f, ax1 = 0.f, ay1 = 0.f;
    float ax2 = 0.f, ay2 = 0.f, ax3 = 0.f, ay3 = 0.f;
    int j = start;
    for (; j + 4 <= end; j += 4) {
        const int s0 = csr[j], s1 = csr[j + 1], s2 = csr[j + 2], s3 = csr[j + 3];
        const float2 t0 = unpack_bf16(zin[(size_t)s0 * 64 + lane]);
        const float2 t1 = unpack_bf16(zin[(size_t)s1 * 64 + lane]);
        const float2 t2 = unpack_bf16(zin[(size_t)s2 * 64 + lane]);
        const float2 t3 = unpack_bf16(zin[(size_t)s3 * 64 + lane]);
        ax0 += t0.x; ay0 += t0.y;
        ax1 += t1.x; ay1 += t1.y;
        ax2 += t2.x; ay2 += t2.y;
        ax3 += t3.x; ay3 += t3.y;
    }
    for (; j < end; ++j) {
        const float2 t0 = unpack_bf16(zin[(size_t)csr[j] * 64 + lane]);
        ax0 += t0.x; ay0 += t0.y;
    }
    const float invd = 1.0f / ((float)(end - start) + 1e-16f);
    const size_t base = (size_t)node * DIM + lane * 2;
    const float2 vv = *(const float2*)&v[base];
    const float2 sk = *(const float2*)&skip[base];
    const float2 lb = *(const float2*)&lin_b[lane * 2];
    float tx = 0.9f * ((ax0 + ax1) + (ax2 + ax3)) * invd + 0.1f * vv.x + sk.x + lb.x;
    float ty = 0.9f * ((ay0 + ay1) + (ay2 + ay3)) * invd + 0.1f * vv.y + sk.y + lb.y;

    float s = tx + ty;
    float q = tx * tx + ty * ty;
    #pragma unroll
    for (int off = 32; off; off >>= 1) {
        s += __shfl_xor(s, off, 64);
        q += __shfl_xor(q, off, 64);
    }
    const float mu   = s * (1.0f / 128.0f);
    const float var  = q * (1.0f / 128.0f) - mu * mu;
    const float rstd = rsqrtf(var + 1e-5f);
    const float2 g = *(const float2*)&ln_g[lane * 2];
    const float2 b = *(const float2*)&ln_b[lane * 2];
    float2 o;
    o.x = (tx - mu) * rstd * g.x + b.x;
    o.y = (ty - mu) * rstd * g.y + b.y;
    *(float2*)&out[base] = o;
}

// ---------------------------------------------------------------------------
extern "C" void kernel_launch(void* const* d_in, const int* in_sizes, int n_in,
                              void* d_out, int out_size, void* d_ws, size_t ws_size,
                              hipStream_t stream) {
    const float* x      = (const float*)d_in[0];
    const int*   e      = (const int*)d_in[1];
    const float* lin_w  = (const float*)d_in[2];
    const float* lin_b  = (const float*)d_in[3];
    const float* skip_w = (const float*)d_in[4];
    const float* ln_g   = (const float*)d_in[5];
    const float* ln_b   = (const float*)d_in[6];
    float* out = (float*)d_out;

    const int* e0 = e;
    const int* e1 = e + M_EDGES;

    // workspace layout
    char* ws = (char*)d_ws;
    const size_t fsz = (size_t)N_NODES * DIM * sizeof(float);       // 51.2 MB
    const size_t hsz = (size_t)N_NODES * DIM * sizeof(short);       // 25.6 MB
    float*  v    = (float*)(ws);
    float*  skip = (float*)(ws + fsz);
    uint32* zA   = (uint32*)(ws + 2 * fsz);
    uint32* zB   = (uint32*)(ws + 2 * fsz + hsz);
    int* deg      = (int*)(ws + 2 * fsz + 2 * hsz);
    int* row_ptr  = deg + N_NODES;
    int* cursor   = row_ptr + (N_NODES + 1);
    int* blk_sums = cursor + N_NODES;
    int* csr      = blk_sums + NBLK_SCAN;

    // ---- CSR build ----
    hipMemsetAsync(deg, 0, N_NODES * sizeof(int), stream);
    deg_hist<<<1024, 256, 0, stream>>>(e0, deg);
    scan_blocks<<<NBLK_SCAN, 1024, 0, stream>>>(deg, row_ptr, blk_sums);
    scan_tops<<<1, 128, 0, stream>>>(blk_sums);
    scan_add<<<NBLK_SCAN, 1024, 0, stream>>>(blk_sums, row_ptr, cursor);
    csr_fill<<<2048, 256, 0, stream>>>(e0, e1, cursor, csr);

    // ---- GEMMs ----
    gemm_xw<<<dim3((N_NODES + GR - 1) / GR, DIM / GC), 256, 0, stream>>>(x, lin_w, v);
    gemm_xw<<<dim3((N_NODES + GR - 1) / GR, DIM / GC), 256, 0, stream>>>(x, skip_w, skip);

    // ---- PPR power iteration (10 steps total) ----
    ppr_init_bf16<<<2048, 256, 0, stream>>>(v, zA);          // z1
    for (int it = 0; it < 8; ++it) {                          // z2..z9
        const uint32* zi = (it & 1) ? zB : zA;
        uint32*       zo = (it & 1) ? zA : zB;
        spmv_bf16<<<N_NODES / 4, 256, 0, stream>>>(row_ptr, csr, zi, v, zo);
    }
    // z9 is in zA; final step z10 fused with skip+bias+LN
    spmv_final_ln<<<N_NODES / 4, 256, 0, stream>>>(row_ptr, csr, zA, v, skip,
                                                   lin_b, ln_g, ln_b, out);
}

// Round 3
// 940.676 us; speedup vs baseline: 1.7495x; 1.2026x over previous
//
#include <hip/hip_runtime.h>
#include <hip/hip_bf16.h>

#define N_NODES 100000
#define M_EDGES 1600000
#define DIM 128
#define NBLK_SCAN ((N_NODES + 1023) / 1024)   // 98

typedef unsigned int uint32;
typedef unsigned short ushort;
typedef __attribute__((ext_vector_type(8))) short short8;
typedef __attribute__((ext_vector_type(4))) float f32x4;
typedef __attribute__((ext_vector_type(2))) float f32x2;

// ---- bf16 helpers (RNE) ----
__device__ __forceinline__ uint32 pack_bf16_pair(float a, float b) {
    uint32 ua = __float_as_uint(a);
    uint32 ub = __float_as_uint(b);
    ua += 0x7fffu + ((ua >> 16) & 1u);
    ub += 0x7fffu + ((ub >> 16) & 1u);
    return (ua >> 16) | (ub & 0xffff0000u);
}
__device__ __forceinline__ ushort bf16_1(float f) {
    uint32 u = __float_as_uint(f);
    u += 0x7fffu + ((u >> 16) & 1u);
    return (ushort)(u >> 16);
}
__device__ __forceinline__ float2 unpack_bf16_pair(uint32 u) {
    float2 r;
    r.x = __uint_as_float(u << 16);
    r.y = __uint_as_float(u & 0xffff0000u);
    return r;
}

// ---- fp8 helpers (HW cvt, self-consistent format on gfx950) ----
__device__ __forceinline__ uint32 pack2_fp8(float a, float b) {
    return (uint32)__builtin_amdgcn_cvt_pk_fp8_f32(a, b, 0, false);
}
__device__ __forceinline__ f32x2 unpack2_fp8(uint32 u) {
    return __builtin_amdgcn_cvt_pk_f32_fp8((int)u, false);
}

// ---------------------------------------------------------------------------
// degree histogram
// ---------------------------------------------------------------------------
__global__ __launch_bounds__(256) void deg_hist(const int* __restrict__ e0,
                                                int* __restrict__ deg) {
    const int stride = gridDim.x * blockDim.x;
    for (int i = blockIdx.x * blockDim.x + threadIdx.x; i < M_EDGES; i += stride)
        atomicAdd(&deg[e0[i]], 1);
}

// ---------------------------------------------------------------------------
// hierarchical scan
// ---------------------------------------------------------------------------
__global__ __launch_bounds__(1024) void scan_blocks(const int* __restrict__ deg,
                                                    int* __restrict__ row_ptr,
                                                    int* __restrict__ blk_sums) {
    __shared__ int woff[16];
    const int tid  = threadIdx.x;
    const int lane = tid & 63;
    const int wid  = tid >> 6;
    const int i    = blockIdx.x * 1024 + tid;
    const int val  = (i < N_NODES) ? deg[i] : 0;
    int incl = val;
    #pragma unroll
    for (int off = 1; off < 64; off <<= 1) {
        int t = __shfl_up(incl, off, 64);
        if (lane >= off) incl += t;
    }
    if (lane == 63) woff[wid] = incl;
    __syncthreads();
    if (wid == 0) {
        int w = (lane < 16) ? woff[lane] : 0;
        int winc = w;
        #pragma unroll
        for (int off = 1; off < 16; off <<= 1) {
            int t = __shfl_up(winc, off, 64);
            if (lane >= off) winc += t;
        }
        if (lane < 16) woff[lane] = winc - w;
    }
    __syncthreads();
    if (i < N_NODES) row_ptr[i] = woff[wid] + incl - val;
    if (tid == 1023) blk_sums[blockIdx.x] = woff[15] + incl;
}

__global__ __launch_bounds__(128) void scan_tops(int* __restrict__ blk_sums) {
    __shared__ int tot0;
    const int tid  = threadIdx.x;
    const int lane = tid & 63;
    const int wid  = tid >> 6;
    const int val  = (tid < NBLK_SCAN) ? blk_sums[tid] : 0;
    int incl = val;
    #pragma unroll
    for (int off = 1; off < 64; off <<= 1) {
        int t = __shfl_up(incl, off, 64);
        if (lane >= off) incl += t;
    }
    if (tid == 63) tot0 = incl;
    __syncthreads();
    const int excl = incl - val + (wid ? tot0 : 0);
    if (tid < NBLK_SCAN) blk_sums[tid] = excl;
}

__global__ __launch_bounds__(1024) void scan_add(const int* __restrict__ blk_sums,
                                                 int* __restrict__ row_ptr,
                                                 int* __restrict__ cursor) {
    const int i = blockIdx.x * 1024 + threadIdx.x;
    if (i < N_NODES) {
        const int r = row_ptr[i] + blk_sums[blockIdx.x];
        row_ptr[i] = r;
        cursor[i]  = r;
    }
    if (i == 0) row_ptr[N_NODES] = M_EDGES;
}

// ---------------------------------------------------------------------------
// CSR fill
// ---------------------------------------------------------------------------
__global__ __launch_bounds__(256) void csr_fill(const int* __restrict__ e0,
                                                const int* __restrict__ e1,
                                                int* __restrict__ cursor,
                                                int* __restrict__ csr) {
    const int stride = gridDim.x * blockDim.x;
    for (int i = blockIdx.x * blockDim.x + threadIdx.x; i < M_EDGES; i += stride) {
        const int pos = atomicAdd(&cursor[e0[i]], 1);
        csr[pos] = e1[i];
    }
}

// ---------------------------------------------------------------------------
// x (fp32) -> xb (bf16).  1.6M threads, 8 elements each (exact).
// ---------------------------------------------------------------------------
__global__ __launch_bounds__(256) void convert_x(const float* __restrict__ x,
                                                 uint32* __restrict__ xb) {
    const int i = blockIdx.x * 256 + threadIdx.x;   // 0 .. 1.6M-1
    const float4 a = ((const float4*)x)[2 * i];
    const float4 b = ((const float4*)x)[2 * i + 1];
    uint4 o;
    o.x = pack_bf16_pair(a.x, a.y);
    o.y = pack_bf16_pair(a.z, a.w);
    o.z = pack_bf16_pair(b.x, b.y);
    o.w = pack_bf16_pair(b.z, b.w);
    ((uint4*)xb)[i] = o;
}

// ---------------------------------------------------------------------------
// Wt (bf16, transposed, concatenated): Wt[c][k]; c<128 -> lin_w, else skip_w
// ---------------------------------------------------------------------------
__global__ __launch_bounds__(256) void convert_w(const float* __restrict__ lin_w,
                                                 const float* __restrict__ skip_w,
                                                 ushort* __restrict__ wt) {
    const int t = blockIdx.x * 256 + threadIdx.x;   // 0 .. 32767
    const int c = t >> 7;
    const int k = t & 127;
    const float val = (c < DIM) ? lin_w[k * DIM + c] : skip_w[k * DIM + (c - DIM)];
    wt[t] = bf16_1(val);
}

// ---------------------------------------------------------------------------
// fused GEMM: [v | skip](bf16) = xb(bf16) @ [lin_w | skip_w]  via MFMA
// block: 64 rows x 256 cols, 4 waves (each wave 64x64), K=128
// ---------------------------------------------------------------------------
__global__ __launch_bounds__(256) void gemm_mfma(const ushort* __restrict__ xb,
                                                 const ushort* __restrict__ wt,
                                                 ushort* __restrict__ vb,
                                                 ushort* __restrict__ skipb) {
    __shared__ short8 As[64 * 16];    // 16 KB, chunk-XOR swizzled
    __shared__ short8 Bs[256 * 16];   // 64 KB, chunk-XOR swizzled
    const int tid  = threadIdx.x;
    const int row0 = blockIdx.x * 64;

    #pragma unroll
    for (int it = 0; it < 4; ++it) {
        const int idx = it * 256 + tid;
        const int r = idx >> 4, c = idx & 15;
        short8 val = (short8)0;
        if (row0 + r < N_NODES)
            val = *(const short8*)&xb[(size_t)(row0 + r) * DIM + c * 8];
        As[r * 16 + (c ^ (r & 7))] = val;
    }
    #pragma unroll
    for (int it = 0; it < 16; ++it) {
        const int idx = it * 256 + tid;
        const int r = idx >> 4, c = idx & 15;
        Bs[r * 16 + (c ^ (r & 7))] = *(const short8*)&wt[(size_t)r * DIM + c * 8];
    }
    __syncthreads();

    const int lane = tid & 63;
    const int wid  = tid >> 6;
    const int n0   = wid * 64;        // output col base of this wave (0..192)
    const int lrow = lane & 15;
    const int lgrp = lane >> 4;

    f32x4 acc[4][4];
    #pragma unroll
    for (int m = 0; m < 4; ++m)
        #pragma unroll
        for (int n = 0; n < 4; ++n) acc[m][n] = (f32x4)0.f;

    #pragma unroll
    for (int kk = 0; kk < 4; ++kk) {
        const int ch = kk * 4 + lgrp;
        short8 a[4], b[4];
        #pragma unroll
        for (int m = 0; m < 4; ++m) {
            const int r = m * 16 + lrow;
            a[m] = As[r * 16 + (ch ^ (r & 7))];
        }
        #pragma unroll
        for (int n = 0; n < 4; ++n) {
            const int r = n0 + n * 16 + lrow;
            b[n] = Bs[r * 16 + (ch ^ (r & 7))];
        }
        #pragma unroll
        for (int m = 0; m < 4; ++m)
            #pragma unroll
            for (int n = 0; n < 4; ++n)
                acc[m][n] = __builtin_amdgcn_mfma_f32_16x16x32_bf16(a[m], b[n], acc[m][n], 0, 0, 0);
    }

    // epilogue: C/D layout col=lane&15, row=(lane>>4)*4+reg
    ushort* dst = (wid < 2) ? vb : skipb;
    const int cbase = (wid < 2) ? n0 : n0 - 128;
    #pragma unroll
    for (int m = 0; m < 4; ++m) {
        #pragma unroll
        for (int n = 0; n < 4; ++n) {
            #pragma unroll
            for (int r = 0; r < 4; ++r) {
                const int row = row0 + m * 16 + lgrp * 4 + r;
                if (row < N_NODES)
                    dst[(size_t)row * DIM + cbase + n * 16 + lrow] = bf16_1(acc[m][n][r]);
            }
        }
    }
}

// ---------------------------------------------------------------------------
// z1 = 0.1 * v, packed to fp8.  3.2M threads, 4 features each (exact).
// ---------------------------------------------------------------------------
__global__ __launch_bounds__(256) void ppr_init_fp8(const uint32* __restrict__ vb,
                                                    uint32* __restrict__ z) {
    const int i = blockIdx.x * 256 + threadIdx.x;   // 0 .. 3.2M-1
    const float2 a = unpack_bf16_pair(vb[2 * i]);
    const float2 b = unpack_bf16_pair(vb[2 * i + 1]);
    int p = __builtin_amdgcn_cvt_pk_fp8_f32(0.1f * a.x, 0.1f * a.y, 0, false);
    p = __builtin_amdgcn_cvt_pk_fp8_f32(0.1f * b.x, 0.1f * b.y, p, true);
    z[i] = (uint32)p;
}

// ---------------------------------------------------------------------------
// one PPR step on fp8 z: zout = fp8(0.9*invd*sum(nbr) + 0.1*v)
// wave per node, lane holds 2 features (ushort -> 128B coalesced row)
// ---------------------------------------------------------------------------
__global__ __launch_bounds__(256) void spmv_fp8(const int* __restrict__ row_ptr,
                                                const int* __restrict__ csr,
                                                const ushort* __restrict__ zin,
                                                const uint32* __restrict__ vb,
                                                ushort* __restrict__ zout) {
    const int node = blockIdx.x * 4 + (threadIdx.x >> 6);
    if (node >= N_NODES) return;
    const int lane  = threadIdx.x & 63;
    const int start = row_ptr[node];
    const int end   = row_ptr[node + 1];
    float ax0 = 0.f, ay0 = 0.f, ax1 = 0.f, ay1 = 0.f;
    float ax2 = 0.f, ay2 = 0.f, ax3 = 0.f, ay3 = 0.f;
    int j = start;
    for (; j + 4 <= end; j += 4) {
        const int s0 = csr[j], s1 = csr[j + 1], s2 = csr[j + 2], s3 = csr[j + 3];
        const f32x2 t0 = unpack2_fp8(zin[(size_t)s0 * 64 + lane]);
        const f32x2 t1 = unpack2_fp8(zin[(size_t)s1 * 64 + lane]);
        const f32x2 t2 = unpack2_fp8(zin[(size_t)s2 * 64 + lane]);
        const f32x2 t3 = unpack2_fp8(zin[(size_t)s3 * 64 + lane]);
        ax0 += t0.x; ay0 += t0.y;
        ax1 += t1.x; ay1 += t1.y;
        ax2 += t2.x; ay2 += t2.y;
        ax3 += t3.x; ay3 += t3.y;
    }
    for (; j < end; ++j) {
        const f32x2 t0 = unpack2_fp8(zin[(size_t)csr[j] * 64 + lane]);
        ax0 += t0.x; ay0 += t0.y;
    }
    const float invd = 1.0f / ((float)(end - start) + 1e-16f);
    const float2 vv = unpack_bf16_pair(vb[(size_t)node * 64 + lane]);
    const float ox = 0.9f * ((ax0 + ax1) + (ax2 + ax3)) * invd + 0.1f * vv.x;
    const float oy = 0.9f * ((ay0 + ay1) + (ay2 + ay3)) * invd + 0.1f * vv.y;
    zout[(size_t)node * 64 + lane] = (ushort)pack2_fp8(ox, oy);
}

// ---------------------------------------------------------------------------
// final PPR step fused with skip + bias + LayerNorm, fp32 out
// ---------------------------------------------------------------------------
__global__ __launch_bounds__(256) void spmv_final_ln(const int* __restrict__ row_ptr,
                                                     const int* __restrict__ csr,
                                                     const ushort* __restrict__ zin,
                                                     const uint32* __restrict__ vb,
                                                     const uint32* __restrict__ skipb,
                                                     const float* __restrict__ lin_b,
                                                     const float* __restrict__ ln_g,
                                                     const float* __restrict__ ln_b,
                                                     float* __restrict__ out) {
    const int node = blockIdx.x * 4 + (threadIdx.x >> 6);
    if (node >= N_NODES) return;
    const int lane  = threadIdx.x & 63;
    const int start = row_ptr[node];
    const int end   = row_ptr[node + 1];
    float ax0 = 0.f, ay0 = 0.f, ax1 = 0.f, ay1 = 0.f;
    float ax2 = 0.f, ay2 = 0.f, ax3 = 0.f, ay3 = 0.f;
    int j = start;
    for (; j + 4 <= end; j += 4) {
        const int s0 = csr[j], s1 = csr[j + 1], s2 = csr[j + 2], s3 = csr[j + 3];
        const f32x2 t0 = unpack2_fp8(zin[(size_t)s0 * 64 + lane]);
        const f32x2 t1 = unpack2_fp8(zin[(size_t)s1 * 64 + lane]);
        const f32x2 t2 = unpack2_fp8(zin[(size_t)s2 * 64 + lane]);
        const f32x2 t3 = unpack2_fp8(zin[(size_t)s3 * 64 + lane]);
        ax0 += t0.x; ay0 += t0.y;
        ax1 += t1.x; ay1 += t1.y;
        ax2 += t2.x; ay2 += t2.y;
        ax3 += t3.x; ay3 += t3.y;
    }
    for (; j < end; ++j) {
        const f32x2 t0 = unpack2_fp8(zin[(size_t)csr[j] * 64 + lane]);
        ax0 += t0.x; ay0 += t0.y;
    }
    const float invd = 1.0f / ((float)(end - start) + 1e-16f);
    const float2 vv = unpack_bf16_pair(vb[(size_t)node * 64 + lane]);
    const float2 sk = unpack_bf16_pair(skipb[(size_t)node * 64 + lane]);
    const float2 lb = *(const float2*)&lin_b[lane * 2];
    float tx = 0.9f * ((ax0 + ax1) + (ax2 + ax3)) * invd + 0.1f * vv.x + sk.x + lb.x;
    float ty = 0.9f * ((ay0 + ay1) + (ay2 + ay3)) * invd + 0.1f * vv.y + sk.y + lb.y;

    float s = tx + ty;
    float q = tx * tx + ty * ty;
    #pragma unroll
    for (int off = 32; off; off >>= 1) {
        s += __shfl_xor(s, off, 64);
        q += __shfl_xor(q, off, 64);
    }
    const float mu   = s * (1.0f / 128.0f);
    const float var  = q * (1.0f / 128.0f) - mu * mu;
    const float rstd = rsqrtf(var + 1e-5f);
    const float2 g = *(const float2*)&ln_g[lane * 2];
    const float2 b = *(const float2*)&ln_b[lane * 2];
    float2 o;
    o.x = (tx - mu) * rstd * g.x + b.x;
    o.y = (ty - mu) * rstd * g.y + b.y;
    *(float2*)&out[(size_t)node * DIM + lane * 2] = o;
}

// ---------------------------------------------------------------------------
extern "C" void kernel_launch(void* const* d_in, const int* in_sizes, int n_in,
                              void* d_out, int out_size, void* d_ws, size_t ws_size,
                              hipStream_t stream) {
    const float* x      = (const float*)d_in[0];
    const int*   e      = (const int*)d_in[1];
    const float* lin_w  = (const float*)d_in[2];
    const float* lin_b  = (const float*)d_in[3];
    const float* skip_w = (const float*)d_in[4];
    const float* ln_g   = (const float*)d_in[5];
    const float* ln_b   = (const float*)d_in[6];
    float* out = (float*)d_out;

    const int* e0 = e;
    const int* e1 = e + M_EDGES;

    // workspace layout
    char* ws = (char*)d_ws;
    const size_t hsz = (size_t)N_NODES * DIM * sizeof(ushort);   // 25.6 MB
    const size_t qsz = (size_t)N_NODES * DIM;                    // 12.8 MB
    ushort* vb    = (ushort*)(ws);
    ushort* skipb = (ushort*)(ws + hsz);
    ushort* xb    = (ushort*)(ws + 2 * hsz);
    ushort* zA    = (ushort*)(ws + 3 * hsz);
    ushort* zB    = (ushort*)(ws + 3 * hsz + qsz);
    ushort* wt    = (ushort*)(ws + 3 * hsz + 2 * qsz);
    char*   ip    = ws + 3 * hsz + 2 * qsz + 65536;
    int* deg      = (int*)ip;
    int* row_ptr  = deg + N_NODES;
    int* cursor   = row_ptr + (N_NODES + 1);
    int* blk_sums = cursor + N_NODES;
    int* csr      = blk_sums + NBLK_SCAN + 1;

    // ---- CSR build ----
    hipMemsetAsync(deg, 0, N_NODES * sizeof(int), stream);
    deg_hist<<<1024, 256, 0, stream>>>(e0, deg);
    scan_blocks<<<NBLK_SCAN, 1024, 0, stream>>>(deg, row_ptr, blk_sums);
    scan_tops<<<1, 128, 0, stream>>>(blk_sums);
    scan_add<<<NBLK_SCAN, 1024, 0, stream>>>(blk_sums, row_ptr, cursor);
    csr_fill<<<2048, 256, 0, stream>>>(e0, e1, cursor, csr);

    // ---- bf16 conversions + fused MFMA GEMM ----
    convert_x<<<(N_NODES * DIM / 8) / 256, 256, 0, stream>>>(x, (uint32*)xb);
    convert_w<<<(2 * DIM * DIM) / 256, 256, 0, stream>>>(lin_w, skip_w, wt);
    gemm_mfma<<<(N_NODES + 63) / 64, 256, 0, stream>>>(xb, wt, vb, skipb);

    // ---- PPR power iteration (10 steps total) ----
    ppr_init_fp8<<<(N_NODES * DIM / 4) / 256, 256, 0, stream>>>((const uint32*)vb, (uint32*)zA);
    for (int it = 0; it < 8; ++it) {                 // z2..z9
        const ushort* zi = (it & 1) ? zB : zA;
        ushort*       zo = (it & 1) ? zA : zB;
        spmv_fp8<<<N_NODES / 4, 256, 0, stream>>>(row_ptr, csr, zi, (const uint32*)vb, zo);
    }
    // z9 in zA; final step fused with skip+bias+LN
    spmv_final_ln<<<N_NODES / 4, 256, 0, stream>>>(row_ptr, csr, zA, (const uint32*)vb,
                                                   (const uint32*)skipb, lin_b, ln_g, ln_b, out);
}

// Round 4
// 802.182 us; speedup vs baseline: 2.0516x; 1.1726x over previous
//
#include <hip/hip_runtime.h>
#include <hip/hip_bf16.h>

#define N_NODES 100000
#define M_EDGES 1600000
#define DIM 128

#define BUCKET_SHIFT 9
#define BUCKET_NODES 512
#define NB 196            // ceil(100000/512)
#define CAP 10240         // per-bucket capacity (mean 8192, +22 sigma)
#define PA_BLOCKS 512
#define PA_CHUNK (M_EDGES / PA_BLOCKS)   // 3125

typedef unsigned int uint32;
typedef unsigned short ushort;
typedef __attribute__((ext_vector_type(8))) short short8;
typedef __attribute__((ext_vector_type(4))) float f32x4;
typedef __attribute__((ext_vector_type(2))) float f32x2;

// ---- bf16 helpers (RNE) ----
__device__ __forceinline__ uint32 pack_bf16_pair(float a, float b) {
    uint32 ua = __float_as_uint(a);
    uint32 ub = __float_as_uint(b);
    ua += 0x7fffu + ((ua >> 16) & 1u);
    ub += 0x7fffu + ((ub >> 16) & 1u);
    return (ua >> 16) | (ub & 0xffff0000u);
}
__device__ __forceinline__ ushort bf16_1(float f) {
    uint32 u = __float_as_uint(f);
    u += 0x7fffu + ((u >> 16) & 1u);
    return (ushort)(u >> 16);
}
__device__ __forceinline__ float2 unpack_bf16_pair(uint32 u) {
    float2 r;
    r.x = __uint_as_float(u << 16);
    r.y = __uint_as_float(u & 0xffff0000u);
    return r;
}

// ---- fp8 helpers (HW cvt on gfx950, self-consistent) ----
__device__ __forceinline__ uint32 pack2_fp8(float a, float b) {
    return (uint32)__builtin_amdgcn_cvt_pk_fp8_f32(a, b, 0, false);
}
__device__ __forceinline__ f32x2 unpack2_fp8(uint32 u) {
    return __builtin_amdgcn_cvt_pk_f32_fp8((int)u, false);
}

// ---------------------------------------------------------------------------
// Pass A: partition edges into 196 dst-buckets.
// Per-block LDS histogram, one global atomic per (block,bucket), then
// chunk-contiguous writes of packed (src<<9 | dst_local).
// ---------------------------------------------------------------------------
__global__ __launch_bounds__(256) void partA(const int* __restrict__ e0,
                                             const int* __restrict__ e1,
                                             int* __restrict__ g_cnt,
                                             uint32* __restrict__ pairs) {
    __shared__ int hist[NB];
    __shared__ int base[NB];
    const int tid = threadIdx.x;
    const int beg = blockIdx.x * PA_CHUNK;
    const int end = beg + PA_CHUNK;
    for (int i = tid; i < NB; i += 256) hist[i] = 0;
    __syncthreads();
    #pragma unroll 4
    for (int i = beg + tid; i < end; i += 256)
        atomicAdd(&hist[e0[i] >> BUCKET_SHIFT], 1);
    __syncthreads();
    for (int i = tid; i < NB; i += 256) {
        base[i] = atomicAdd(&g_cnt[i], hist[i]);
        hist[i] = 0;            // reuse as local cursor
    }
    __syncthreads();
    #pragma unroll 4
    for (int i = beg + tid; i < end; i += 256) {
        const int d = e0[i];
        const int s = e1[i];
        const int b = d >> BUCKET_SHIFT;
        const int off = atomicAdd(&hist[b], 1);
        pairs[b * CAP + base[b] + off] =
            ((uint32)s << BUCKET_SHIFT) | (uint32)(d & (BUCKET_NODES - 1));
    }
}

// ---------------------------------------------------------------------------
// exclusive scan of 196 bucket counts -> g_base; also row_ptr[N] = M
// ---------------------------------------------------------------------------
__global__ __launch_bounds__(256) void bucket_scan(const int* __restrict__ g_cnt,
                                                   int* __restrict__ g_base,
                                                   int* __restrict__ row_ptr) {
    __shared__ int woff[4];
    const int tid  = threadIdx.x;
    const int lane = tid & 63;
    const int wid  = tid >> 6;
    const int val  = (tid < NB) ? g_cnt[tid] : 0;
    int incl = val;
    #pragma unroll
    for (int o = 1; o < 64; o <<= 1) {
        int t = __shfl_up(incl, o, 64);
        if (lane >= o) incl += t;
    }
    if (lane == 63) woff[wid] = incl;
    __syncthreads();
    if (tid == 0) {
        int a = woff[0], b = woff[1], c = woff[2];
        woff[0] = 0; woff[1] = a; woff[2] = a + b; woff[3] = a + b + c;
    }
    __syncthreads();
    if (tid < NB) g_base[tid] = woff[wid] + incl - val;
    if (tid == 0) row_ptr[N_NODES] = M_EDGES;
}

// ---------------------------------------------------------------------------
// Pass B: one block per bucket. LDS degree hist -> 512-wide LDS scan ->
// row_ptr write + LDS-cursor scatter of csr into the bucket's region.
// ---------------------------------------------------------------------------
__global__ __launch_bounds__(256) void partB(const int* __restrict__ g_cnt,
                                             const int* __restrict__ g_base,
                                             const uint32* __restrict__ pairs,
                                             int* __restrict__ row_ptr,
                                             int* __restrict__ csr) {
    __shared__ int deg[BUCKET_NODES];
    __shared__ int off[BUCKET_NODES];
    __shared__ int woff[4];
    const int b     = blockIdx.x;
    const int cnt   = g_cnt[b];
    const int gbase = g_base[b];
    const int n0    = b << BUCKET_SHIFT;
    const int tid   = threadIdx.x;
    deg[tid] = 0;
    deg[tid + 256] = 0;
    __syncthreads();
    #pragma unroll 4
    for (int j = tid; j < cnt; j += 256)
        atomicAdd(&deg[pairs[b * CAP + j] & (BUCKET_NODES - 1)], 1);
    __syncthreads();
    // exclusive scan of 512 degrees (2 elements/thread)
    const int lane = tid & 63;
    const int wid  = tid >> 6;
    const int d0 = deg[2 * tid];
    const int d1 = deg[2 * tid + 1];
    const int sum = d0 + d1;
    int incl = sum;
    #pragma unroll
    for (int o = 1; o < 64; o <<= 1) {
        int t = __shfl_up(incl, o, 64);
        if (lane >= o) incl += t;
    }
    if (lane == 63) woff[wid] = incl;
    __syncthreads();
    if (tid == 0) {
        int a = woff[0], bb = woff[1], c = woff[2];
        woff[0] = 0; woff[1] = a; woff[2] = a + bb; woff[3] = a + bb + c;
    }
    __syncthreads();
    const int excl = woff[wid] + incl - sum;
    off[2 * tid]     = excl;
    off[2 * tid + 1] = excl + d0;
    const int node0 = n0 + 2 * tid;
    if (node0 < N_NODES)     row_ptr[node0]     = gbase + excl;
    if (node0 + 1 < N_NODES) row_ptr[node0 + 1] = gbase + excl + d0;
    __syncthreads();
    #pragma unroll 4
    for (int j = tid; j < cnt; j += 256) {
        const uint32 code = pairs[b * CAP + j];
        const int l = code & (BUCKET_NODES - 1);
        const int p = atomicAdd(&off[l], 1);
        csr[gbase + p] = (int)(code >> BUCKET_SHIFT);
    }
}

// ---------------------------------------------------------------------------
// x (fp32) -> xb (bf16).  8 elements/thread.
// ---------------------------------------------------------------------------
__global__ __launch_bounds__(256) void convert_x(const float* __restrict__ x,
                                                 uint32* __restrict__ xb) {
    const int i = blockIdx.x * 256 + threadIdx.x;
    const float4 a = ((const float4*)x)[2 * i];
    const float4 b = ((const float4*)x)[2 * i + 1];
    uint4 o;
    o.x = pack_bf16_pair(a.x, a.y);
    o.y = pack_bf16_pair(a.z, a.w);
    o.z = pack_bf16_pair(b.x, b.y);
    o.w = pack_bf16_pair(b.z, b.w);
    ((uint4*)xb)[i] = o;
}

// ---------------------------------------------------------------------------
// Wt (bf16, transposed, concatenated): c<128 -> lin_w col, else skip_w col
// ---------------------------------------------------------------------------
__global__ __launch_bounds__(256) void convert_w(const float* __restrict__ lin_w,
                                                 const float* __restrict__ skip_w,
                                                 ushort* __restrict__ wt) {
    const int t = blockIdx.x * 256 + threadIdx.x;
    const int c = t >> 7;
    const int k = t & 127;
    const float val = (c < DIM) ? lin_w[k * DIM + c] : skip_w[k * DIM + (c - DIM)];
    wt[t] = bf16_1(val);
}

// ---------------------------------------------------------------------------
// fused GEMM: [v | skip](bf16) = xb @ [lin_w | skip_w]  via MFMA 16x16x32
// ---------------------------------------------------------------------------
__global__ __launch_bounds__(256) void gemm_mfma(const ushort* __restrict__ xb,
                                                 const ushort* __restrict__ wt,
                                                 ushort* __restrict__ vb,
                                                 ushort* __restrict__ skipb) {
    __shared__ short8 As[64 * 16];
    __shared__ short8 Bs[256 * 16];
    const int tid  = threadIdx.x;
    const int row0 = blockIdx.x * 64;

    #pragma unroll
    for (int it = 0; it < 4; ++it) {
        const int idx = it * 256 + tid;
        const int r = idx >> 4, c = idx & 15;
        short8 val = (short8)0;
        if (row0 + r < N_NODES)
            val = *(const short8*)&xb[(size_t)(row0 + r) * DIM + c * 8];
        As[r * 16 + (c ^ (r & 7))] = val;
    }
    #pragma unroll
    for (int it = 0; it < 16; ++it) {
        const int idx = it * 256 + tid;
        const int r = idx >> 4, c = idx & 15;
        Bs[r * 16 + (c ^ (r & 7))] = *(const short8*)&wt[(size_t)r * DIM + c * 8];
    }
    __syncthreads();

    const int lane = tid & 63;
    const int wid  = tid >> 6;
    const int n0   = wid * 64;
    const int lrow = lane & 15;
    const int lgrp = lane >> 4;

    f32x4 acc[4][4];
    #pragma unroll
    for (int m = 0; m < 4; ++m)
        #pragma unroll
        for (int n = 0; n < 4; ++n) acc[m][n] = (f32x4)0.f;

    #pragma unroll
    for (int kk = 0; kk < 4; ++kk) {
        const int ch = kk * 4 + lgrp;
        short8 a[4], b[4];
        #pragma unroll
        for (int m = 0; m < 4; ++m) {
            const int r = m * 16 + lrow;
            a[m] = As[r * 16 + (ch ^ (r & 7))];
        }
        #pragma unroll
        for (int n = 0; n < 4; ++n) {
            const int r = n0 + n * 16 + lrow;
            b[n] = Bs[r * 16 + (ch ^ (r & 7))];
        }
        #pragma unroll
        for (int m = 0; m < 4; ++m)
            #pragma unroll
            for (int n = 0; n < 4; ++n)
                acc[m][n] = __builtin_amdgcn_mfma_f32_16x16x32_bf16(a[m], b[n], acc[m][n], 0, 0, 0);
    }

    ushort* dst = (wid < 2) ? vb : skipb;
    const int cbase = (wid < 2) ? n0 : n0 - 128;
    #pragma unroll
    for (int m = 0; m < 4; ++m) {
        #pragma unroll
        for (int n = 0; n < 4; ++n) {
            #pragma unroll
            for (int r = 0; r < 4; ++r) {
                const int row = row0 + m * 16 + lgrp * 4 + r;
                if (row < N_NODES)
                    dst[(size_t)row * DIM + cbase + n * 16 + lrow] = bf16_1(acc[m][n][r]);
            }
        }
    }
}

// ---------------------------------------------------------------------------
// z1 = 0.1 * v -> fp8
// ---------------------------------------------------------------------------
__global__ __launch_bounds__(256) void ppr_init_fp8(const uint32* __restrict__ vb,
                                                    uint32* __restrict__ z) {
    const int i = blockIdx.x * 256 + threadIdx.x;
    const float2 a = unpack_bf16_pair(vb[2 * i]);
    const float2 b = unpack_bf16_pair(vb[2 * i + 1]);
    int p = __builtin_amdgcn_cvt_pk_fp8_f32(0.1f * a.x, 0.1f * a.y, 0, false);
    p = __builtin_amdgcn_cvt_pk_fp8_f32(0.1f * b.x, 0.1f * b.y, p, true);
    z[i] = (uint32)p;
}

// ---------------------------------------------------------------------------
// one PPR step on fp8 z
// ---------------------------------------------------------------------------
__global__ __launch_bounds__(256) void spmv_fp8(const int* __restrict__ row_ptr,
                                                const int* __restrict__ csr,
                                                const ushort* __restrict__ zin,
                                                const uint32* __restrict__ vb,
                                                ushort* __restrict__ zout) {
    const int node = blockIdx.x * 4 + (threadIdx.x >> 6);
    if (node >= N_NODES) return;
    const int lane  = threadIdx.x & 63;
    const int start = row_ptr[node];
    const int end   = row_ptr[node + 1];
    float ax0 = 0.f, ay0 = 0.f, ax1 = 0.f, ay1 = 0.f;
    float ax2 = 0.f, ay2 = 0.f, ax3 = 0.f, ay3 = 0.f;
    int j = start;
    for (; j + 4 <= end; j += 4) {
        const int s0 = csr[j], s1 = csr[j + 1], s2 = csr[j + 2], s3 = csr[j + 3];
        const f32x2 t0 = unpack2_fp8(zin[(size_t)s0 * 64 + lane]);
        const f32x2 t1 = unpack2_fp8(zin[(size_t)s1 * 64 + lane]);
        const f32x2 t2 = unpack2_fp8(zin[(size_t)s2 * 64 + lane]);
        const f32x2 t3 = unpack2_fp8(zin[(size_t)s3 * 64 + lane]);
        ax0 += t0.x; ay0 += t0.y;
        ax1 += t1.x; ay1 += t1.y;
        ax2 += t2.x; ay2 += t2.y;
        ax3 += t3.x; ay3 += t3.y;
    }
    for (; j < end; ++j) {
        const f32x2 t0 = unpack2_fp8(zin[(size_t)csr[j] * 64 + lane]);
        ax0 += t0.x; ay0 += t0.y;
    }
    const float invd = 1.0f / ((float)(end - start) + 1e-16f);
    const float2 vv = unpack_bf16_pair(vb[(size_t)node * 64 + lane]);
    const float ox = 0.9f * ((ax0 + ax1) + (ax2 + ax3)) * invd + 0.1f * vv.x;
    const float oy = 0.9f * ((ay0 + ay1) + (ay2 + ay3)) * invd + 0.1f * vv.y;
    zout[(size_t)node * 64 + lane] = (ushort)pack2_fp8(ox, oy);
}

// ---------------------------------------------------------------------------
// final PPR step fused with skip + bias + LayerNorm, fp32 out
// ---------------------------------------------------------------------------
__global__ __launch_bounds__(256) void spmv_final_ln(const int* __restrict__ row_ptr,
                                                     const int* __restrict__ csr,
                                                     const ushort* __restrict__ zin,
                                                     const uint32* __restrict__ vb,
                                                     const uint32* __restrict__ skipb,
                                                     const float* __restrict__ lin_b,
                                                     const float* __restrict__ ln_g,
                                                     const float* __restrict__ ln_b,
                                                     float* __restrict__ out) {
    const int node = blockIdx.x * 4 + (threadIdx.x >> 6);
    if (node >= N_NODES) return;
    const int lane  = threadIdx.x & 63;
    const int start = row_ptr[node];
    const int end   = row_ptr[node + 1];
    float ax0 = 0.f, ay0 = 0.f, ax1 = 0.f, ay1 = 0.f;
    float ax2 = 0.f, ay2 = 0.f, ax3 = 0.f, ay3 = 0.f;
    int j = start;
    for (; j + 4 <= end; j += 4) {
        const int s0 = csr[j], s1 = csr[j + 1], s2 = csr[j + 2], s3 = csr[j + 3];
        const f32x2 t0 = unpack2_fp8(zin[(size_t)s0 * 64 + lane]);
        const f32x2 t1 = unpack2_fp8(zin[(size_t)s1 * 64 + lane]);
        const f32x2 t2 = unpack2_fp8(zin[(size_t)s2 * 64 + lane]);
        const f32x2 t3 = unpack2_fp8(zin[(size_t)s3 * 64 + lane]);
        ax0 += t0.x; ay0 += t0.y;
        ax1 += t1.x; ay1 += t1.y;
        ax2 += t2.x; ay2 += t2.y;
        ax3 += t3.x; ay3 += t3.y;
    }
    for (; j < end; ++j) {
        const f32x2 t0 = unpack2_fp8(zin[(size_t)csr[j] * 64 + lane]);
        ax0 += t0.x; ay0 += t0.y;
    }
    const float invd = 1.0f / ((float)(end - start) + 1e-16f);
    const float2 vv = unpack_bf16_pair(vb[(size_t)node * 64 + lane]);
    const float2 sk = unpack_bf16_pair(skipb[(size_t)node * 64 + lane]);
    const float2 lb = *(const float2*)&lin_b[lane * 2];
    float tx = 0.9f * ((ax0 + ax1) + (ax2 + ax3)) * invd + 0.1f * vv.x + sk.x + lb.x;
    float ty = 0.9f * ((ay0 + ay1) + (ay2 + ay3)) * invd + 0.1f * vv.y + sk.y + lb.y;

    float s = tx + ty;
    float q = tx * tx + ty * ty;
    #pragma unroll
    for (int off = 32; off; off >>= 1) {
        s += __shfl_xor(s, off, 64);
        q += __shfl_xor(q, off, 64);
    }
    const float mu   = s * (1.0f / 128.0f);
    const float var  = q * (1.0f / 128.0f) - mu * mu;
    const float rstd = rsqrtf(var + 1e-5f);
    const float2 g = *(const float2*)&ln_g[lane * 2];
    const float2 b = *(const float2*)&ln_b[lane * 2];
    float2 o;
    o.x = (tx - mu) * rstd * g.x + b.x;
    o.y = (ty - mu) * rstd * g.y + b.y;
    *(float2*)&out[(size_t)node * DIM + lane * 2] = o;
}

// ---------------------------------------------------------------------------
extern "C" void kernel_launch(void* const* d_in, const int* in_sizes, int n_in,
                              void* d_out, int out_size, void* d_ws, size_t ws_size,
                              hipStream_t stream) {
    const float* x      = (const float*)d_in[0];
    const int*   e      = (const int*)d_in[1];
    const float* lin_w  = (const float*)d_in[2];
    const float* lin_b  = (const float*)d_in[3];
    const float* skip_w = (const float*)d_in[4];
    const float* ln_g   = (const float*)d_in[5];
    const float* ln_b   = (const float*)d_in[6];
    float* out = (float*)d_out;

    const int* e0 = e;
    const int* e1 = e + M_EDGES;

    // workspace layout
    char* ws = (char*)d_ws;
    const size_t hsz = (size_t)N_NODES * DIM * sizeof(ushort);   // 25.6 MB
    const size_t qsz = (size_t)N_NODES * DIM;                    // 12.8 MB
    const size_t psz = (size_t)NB * CAP * sizeof(uint32);        // 8.03 MB
    ushort* vb    = (ushort*)(ws);
    ushort* skipb = (ushort*)(ws + hsz);
    ushort* xb    = (ushort*)(ws + 2 * hsz);
    ushort* zA    = (ushort*)(ws + 3 * hsz);
    ushort* zB    = (ushort*)(ws + 3 * hsz + qsz);
    ushort* wt    = (ushort*)(ws + 3 * hsz + 2 * qsz);
    uint32* pairs = (uint32*)(ws + 3 * hsz + 2 * qsz + 65536);
    int* row_ptr  = (int*)(ws + 3 * hsz + 2 * qsz + 65536 + psz);
    int* g_cnt    = row_ptr + (N_NODES + 1);
    int* g_base   = g_cnt + NB;
    int* csr      = g_base + NB + 2;

    // ---- CSR build (bucketed, LDS-atomic) ----
    hipMemsetAsync(g_cnt, 0, NB * sizeof(int), stream);
    partA<<<PA_BLOCKS, 256, 0, stream>>>(e0, e1, g_cnt, pairs);
    bucket_scan<<<1, 256, 0, stream>>>(g_cnt, g_base, row_ptr);
    partB<<<NB, 256, 0, stream>>>(g_cnt, g_base, pairs, row_ptr, csr);

    // ---- bf16 conversions + fused MFMA GEMM ----
    convert_x<<<(N_NODES * DIM / 8) / 256, 256, 0, stream>>>(x, (uint32*)xb);
    convert_w<<<(2 * DIM * DIM) / 256, 256, 0, stream>>>(lin_w, skip_w, wt);
    gemm_mfma<<<(N_NODES + 63) / 64, 256, 0, stream>>>(xb, wt, vb, skipb);

    // ---- PPR power iteration (10 steps total) ----
    ppr_init_fp8<<<(N_NODES * DIM / 4) / 256, 256, 0, stream>>>((const uint32*)vb, (uint32*)zA);
    for (int it = 0; it < 8; ++it) {                 // z2..z9
        const ushort* zi = (it & 1) ? zB : zA;
        ushort*       zo = (it & 1) ? zA : zB;
        spmv_fp8<<<N_NODES / 4, 256, 0, stream>>>(row_ptr, csr, zi, (const uint32*)vb, zo);
    }
    // z9 in zA; final step fused with skip+bias+LN
    spmv_final_ln<<<N_NODES / 4, 256, 0, stream>>>(row_ptr, csr, zA, (const uint32*)vb,
                                                   (const uint32*)skipb, lin_b, ln_g, ln_b, out);
}

// Round 5
// 703.722 us; speedup vs baseline: 2.3386x; 1.1399x over previous
//
#include <hip/hip_runtime.h>
#include <hip/hip_bf16.h>

#define N_NODES 100000
#define M_EDGES 1600000
#define DIM 128

#define BUCKET_SHIFT 9
#define BUCKET_NODES 512
#define NB 196            // ceil(100000/512)
#define CAP 10240         // per-bucket capacity (mean 8163)
#define PA_BLOCKS 512
#define PA_CHUNK (M_EDGES / PA_BLOCKS)   // 3125

typedef unsigned int uint32;
typedef unsigned short ushort;
typedef __attribute__((ext_vector_type(8))) short short8;
typedef __attribute__((ext_vector_type(4))) float f32x4;
typedef __attribute__((ext_vector_type(2))) float f32x2;

// ---- bf16 helpers (RNE) ----
__device__ __forceinline__ uint32 pack_bf16_pair(float a, float b) {
    uint32 ua = __float_as_uint(a);
    uint32 ub = __float_as_uint(b);
    ua += 0x7fffu + ((ua >> 16) & 1u);
    ub += 0x7fffu + ((ub >> 16) & 1u);
    return (ua >> 16) | (ub & 0xffff0000u);
}
__device__ __forceinline__ ushort bf16_1(float f) {
    uint32 u = __float_as_uint(f);
    u += 0x7fffu + ((u >> 16) & 1u);
    return (ushort)(u >> 16);
}
__device__ __forceinline__ float2 unpack_bf16_pair(uint32 u) {
    float2 r;
    r.x = __uint_as_float(u << 16);
    r.y = __uint_as_float(u & 0xffff0000u);
    return r;
}

// ---- fp8 helpers (HW cvt on gfx950) ----
__device__ __forceinline__ uint32 pack4_fp8(float a, float b, float c, float d) {
    int p = __builtin_amdgcn_cvt_pk_fp8_f32(a, b, 0, false);
    p = __builtin_amdgcn_cvt_pk_fp8_f32(c, d, p, true);
    return (uint32)p;
}
__device__ __forceinline__ float4 unpack4_fp8(uint32 u) {
    const f32x2 lo = __builtin_amdgcn_cvt_pk_f32_fp8((int)u, false);
    const f32x2 hi = __builtin_amdgcn_cvt_pk_f32_fp8((int)u, true);
    return make_float4(lo.x, lo.y, hi.x, hi.y);
}

// ---------------------------------------------------------------------------
// Pass A: partition edges into 196 dst-buckets (LDS hist + chunked writes)
// ---------------------------------------------------------------------------
__global__ __launch_bounds__(256) void partA(const int* __restrict__ e0,
                                             const int* __restrict__ e1,
                                             int* __restrict__ g_cnt,
                                             uint32* __restrict__ pairs) {
    __shared__ int hist[NB];
    __shared__ int base[NB];
    const int tid = threadIdx.x;
    const int beg = blockIdx.x * PA_CHUNK;
    const int end = beg + PA_CHUNK;
    for (int i = tid; i < NB; i += 256) hist[i] = 0;
    __syncthreads();
    #pragma unroll 4
    for (int i = beg + tid; i < end; i += 256)
        atomicAdd(&hist[e0[i] >> BUCKET_SHIFT], 1);
    __syncthreads();
    for (int i = tid; i < NB; i += 256) {
        base[i] = atomicAdd(&g_cnt[i], hist[i]);
        hist[i] = 0;            // reuse as local cursor
    }
    __syncthreads();
    #pragma unroll 4
    for (int i = beg + tid; i < end; i += 256) {
        const int d = e0[i];
        const int s = e1[i];
        const int b = d >> BUCKET_SHIFT;
        const int off = atomicAdd(&hist[b], 1);
        pairs[b * CAP + base[b] + off] =
            ((uint32)s << BUCKET_SHIFT) | (uint32)(d & (BUCKET_NODES - 1));
    }
}

// ---------------------------------------------------------------------------
// exclusive scan of 196 bucket counts -> g_base; row_ptr[N] = M
// ---------------------------------------------------------------------------
__global__ __launch_bounds__(256) void bucket_scan(const int* __restrict__ g_cnt,
                                                   int* __restrict__ g_base,
                                                   int* __restrict__ row_ptr) {
    __shared__ int woff[4];
    const int tid  = threadIdx.x;
    const int lane = tid & 63;
    const int wid  = tid >> 6;
    const int val  = (tid < NB) ? g_cnt[tid] : 0;
    int incl = val;
    #pragma unroll
    for (int o = 1; o < 64; o <<= 1) {
        int t = __shfl_up(incl, o, 64);
        if (lane >= o) incl += t;
    }
    if (lane == 63) woff[wid] = incl;
    __syncthreads();
    if (tid == 0) {
        int a = woff[0], b = woff[1], c = woff[2];
        woff[0] = 0; woff[1] = a; woff[2] = a + b; woff[3] = a + b + c;
    }
    __syncthreads();
    if (tid < NB) g_base[tid] = woff[wid] + incl - val;
    if (tid == 0) row_ptr[N_NODES] = M_EDGES;
}

// ---------------------------------------------------------------------------
// Pass B: one block per bucket -> row_ptr + csr
// ---------------------------------------------------------------------------
__global__ __launch_bounds__(256) void partB(const int* __restrict__ g_cnt,
                                             const int* __restrict__ g_base,
                                             const uint32* __restrict__ pairs,
                                             int* __restrict__ row_ptr,
                                             int* __restrict__ csr) {
    __shared__ int deg[BUCKET_NODES];
    __shared__ int off[BUCKET_NODES];
    __shared__ int woff[4];
    const int b     = blockIdx.x;
    const int cnt   = g_cnt[b];
    const int gbase = g_base[b];
    const int n0    = b << BUCKET_SHIFT;
    const int tid   = threadIdx.x;
    deg[tid] = 0;
    deg[tid + 256] = 0;
    __syncthreads();
    #pragma unroll 4
    for (int j = tid; j < cnt; j += 256)
        atomicAdd(&deg[pairs[b * CAP + j] & (BUCKET_NODES - 1)], 1);
    __syncthreads();
    const int lane = tid & 63;
    const int wid  = tid >> 6;
    const int d0 = deg[2 * tid];
    const int d1 = deg[2 * tid + 1];
    const int sum = d0 + d1;
    int incl = sum;
    #pragma unroll
    for (int o = 1; o < 64; o <<= 1) {
        int t = __shfl_up(incl, o, 64);
        if (lane >= o) incl += t;
    }
    if (lane == 63) woff[wid] = incl;
    __syncthreads();
    if (tid == 0) {
        int a = woff[0], bb = woff[1], c = woff[2];
        woff[0] = 0; woff[1] = a; woff[2] = a + bb; woff[3] = a + bb + c;
    }
    __syncthreads();
    const int excl = woff[wid] + incl - sum;
    off[2 * tid]     = excl;
    off[2 * tid + 1] = excl + d0;
    const int node0 = n0 + 2 * tid;
    if (node0 < N_NODES)     row_ptr[node0]     = gbase + excl;
    if (node0 + 1 < N_NODES) row_ptr[node0 + 1] = gbase + excl + d0;
    __syncthreads();
    #pragma unroll 4
    for (int j = tid; j < cnt; j += 256) {
        const uint32 code = pairs[b * CAP + j];
        const int l = code & (BUCKET_NODES - 1);
        const int p = atomicAdd(&off[l], 1);
        csr[gbase + p] = (int)(code >> BUCKET_SHIFT);
    }
}

// ---------------------------------------------------------------------------
// Wt (bf16, transposed, concatenated): c<128 -> lin_w col, else skip_w col
// ---------------------------------------------------------------------------
__global__ __launch_bounds__(256) void convert_w(const float* __restrict__ lin_w,
                                                 const float* __restrict__ skip_w,
                                                 ushort* __restrict__ wt) {
    const int t = blockIdx.x * 256 + threadIdx.x;
    const int c = t >> 7;
    const int k = t & 127;
    const float val = (c < DIM) ? lin_w[k * DIM + c] : skip_w[k * DIM + (c - DIM)];
    wt[t] = bf16_1(val);
}

// ---------------------------------------------------------------------------
// fused GEMM: [v | skip](bf16) = x(fp32->bf16 on the fly) @ [lin_w | skip_w]
// ---------------------------------------------------------------------------
__global__ __launch_bounds__(256) void gemm_mfma(const float* __restrict__ x,
                                                 const ushort* __restrict__ wt,
                                                 ushort* __restrict__ vb,
                                                 ushort* __restrict__ skipb) {
    __shared__ uint4 As[64 * 16];     // bf16x8 chunks, XOR-swizzled
    __shared__ uint4 Bs[256 * 16];
    const int tid  = threadIdx.x;
    const int row0 = blockIdx.x * 64;

    #pragma unroll
    for (int it = 0; it < 4; ++it) {
        const int idx = it * 256 + tid;
        const int r = idx >> 4, c = idx & 15;
        const int row = row0 + r;
        uint4 o = make_uint4(0, 0, 0, 0);
        if (row < N_NODES) {
            const float4 f0 = *(const float4*)&x[(size_t)row * DIM + c * 8];
            const float4 f1 = *(const float4*)&x[(size_t)row * DIM + c * 8 + 4];
            o.x = pack_bf16_pair(f0.x, f0.y);
            o.y = pack_bf16_pair(f0.z, f0.w);
            o.z = pack_bf16_pair(f1.x, f1.y);
            o.w = pack_bf16_pair(f1.z, f1.w);
        }
        As[r * 16 + (c ^ (r & 7))] = o;
    }
    #pragma unroll
    for (int it = 0; it < 16; ++it) {
        const int idx = it * 256 + tid;
        const int r = idx >> 4, c = idx & 15;
        Bs[r * 16 + (c ^ (r & 7))] = *(const uint4*)&wt[(size_t)r * DIM + c * 8];
    }
    __syncthreads();

    const int lane = tid & 63;
    const int wid  = tid >> 6;
    const int n0   = wid * 64;
    const int lrow = lane & 15;
    const int lgrp = lane >> 4;

    f32x4 acc[4][4];
    #pragma unroll
    for (int m = 0; m < 4; ++m)
        #pragma unroll
        for (int n = 0; n < 4; ++n) acc[m][n] = (f32x4)0.f;

    #pragma unroll
    for (int kk = 0; kk < 4; ++kk) {
        const int ch = kk * 4 + lgrp;
        short8 a[4], b[4];
        #pragma unroll
        for (int m = 0; m < 4; ++m) {
            const int r = m * 16 + lrow;
            a[m] = *(const short8*)&As[r * 16 + (ch ^ (r & 7))];
        }
        #pragma unroll
        for (int n = 0; n < 4; ++n) {
            const int r = n0 + n * 16 + lrow;
            b[n] = *(const short8*)&Bs[r * 16 + (ch ^ (r & 7))];
        }
        #pragma unroll
        for (int m = 0; m < 4; ++m)
            #pragma unroll
            for (int n = 0; n < 4; ++n)
                acc[m][n] = __builtin_amdgcn_mfma_f32_16x16x32_bf16(a[m], b[n], acc[m][n], 0, 0, 0);
    }

    ushort* dst = (wid < 2) ? vb : skipb;
    const int cbase = (wid < 2) ? n0 : n0 - 128;
    #pragma unroll
    for (int m = 0; m < 4; ++m) {
        #pragma unroll
        for (int n = 0; n < 4; ++n) {
            #pragma unroll
            for (int r = 0; r < 4; ++r) {
                const int row = row0 + m * 16 + lgrp * 4 + r;
                if (row < N_NODES)
                    dst[(size_t)row * DIM + cbase + n * 16 + lrow] = bf16_1(acc[m][n][r]);
            }
        }
    }
}

// ---------------------------------------------------------------------------
// z1 = 0.1 * v -> fp8
// ---------------------------------------------------------------------------
__global__ __launch_bounds__(256) void ppr_init_fp8(const uint32* __restrict__ vb,
                                                    uint32* __restrict__ z) {
    const int i = blockIdx.x * 256 + threadIdx.x;
    const float2 a = unpack_bf16_pair(vb[2 * i]);
    const float2 b = unpack_bf16_pair(vb[2 * i + 1]);
    z[i] = pack4_fp8(0.1f * a.x, 0.1f * a.y, 0.1f * b.x, 0.1f * b.y);
}

// ---------------------------------------------------------------------------
// one PPR step on fp8 z.  2 nodes per wave: half-wave = 32 lanes x 4 features.
// Uniform loop to min(cntA,cntB), predicated tail to max.
// ---------------------------------------------------------------------------
__global__ __launch_bounds__(256) void spmv_fp8(const int* __restrict__ row_ptr,
                                                const int* __restrict__ csr,
                                                const uint32* __restrict__ zin,
                                                const uint32* __restrict__ vb,
                                                uint32* __restrict__ zout) {
    const int node = blockIdx.x * 8 + (threadIdx.x >> 5);
    const int l    = threadIdx.x & 31;
    const int start = row_ptr[node];
    const int cnt   = row_ptr[node + 1] - start;
    const int ocnt  = __shfl_xor(cnt, 32, 64);
    const int mn = min(cnt, ocnt);
    const int mx = max(cnt, ocnt);

    float4 acc0 = make_float4(0.f, 0.f, 0.f, 0.f);
    float4 acc1 = make_float4(0.f, 0.f, 0.f, 0.f);
    int k = 0;
    #pragma unroll 2
    for (; k + 4 <= mn; k += 4) {
        const int j = start + k;
        const int s0 = csr[j], s1 = csr[j + 1], s2 = csr[j + 2], s3 = csr[j + 3];
        const uint32 w0 = zin[(s0 << 5) + l];
        const uint32 w1 = zin[(s1 << 5) + l];
        const uint32 w2 = zin[(s2 << 5) + l];
        const uint32 w3 = zin[(s3 << 5) + l];
        const float4 u0 = unpack4_fp8(w0);
        const float4 u1 = unpack4_fp8(w1);
        const float4 u2 = unpack4_fp8(w2);
        const float4 u3 = unpack4_fp8(w3);
        acc0.x += u0.x + u1.x; acc0.y += u0.y + u1.y;
        acc0.z += u0.z + u1.z; acc0.w += u0.w + u1.w;
        acc1.x += u2.x + u3.x; acc1.y += u2.y + u3.y;
        acc1.z += u2.z + u3.z; acc1.w += u2.w + u3.w;
    }
    for (; k < mx; ++k) {
        const bool valid = k < cnt;
        const int j = valid ? start + k : 0;
        const int s = csr[j];
        const float4 u = unpack4_fp8(zin[(s << 5) + l]);
        if (valid) {
            acc0.x += u.x; acc0.y += u.y; acc0.z += u.z; acc0.w += u.w;
        }
    }
    const float invd = 0.9f / ((float)cnt + 1e-16f);
    const uint2 vv2 = *(const uint2*)&vb[(size_t)node * 64 + 2 * l];
    const float2 va = unpack_bf16_pair(vv2.x);
    const float2 vbp = unpack_bf16_pair(vv2.y);
    const float ox = (acc0.x + acc1.x) * invd + 0.1f * va.x;
    const float oy = (acc0.y + acc1.y) * invd + 0.1f * va.y;
    const float oz = (acc0.z + acc1.z) * invd + 0.1f * vbp.x;
    const float ow = (acc0.w + acc1.w) * invd + 0.1f * vbp.y;
    zout[(node << 5) + l] = pack4_fp8(ox, oy, oz, ow);
}

// ---------------------------------------------------------------------------
// final PPR step fused with skip + bias + LayerNorm, fp32 out
// ---------------------------------------------------------------------------
__global__ __launch_bounds__(256) void spmv_final_ln(const int* __restrict__ row_ptr,
                                                     const int* __restrict__ csr,
                                                     const uint32* __restrict__ zin,
                                                     const uint32* __restrict__ vb,
                                                     const uint32* __restrict__ skipb,
                                                     const float* __restrict__ lin_b,
                                                     const float* __restrict__ ln_g,
                                                     const float* __restrict__ ln_b,
                                                     float* __restrict__ out) {
    const int node = blockIdx.x * 8 + (threadIdx.x >> 5);
    const int l    = threadIdx.x & 31;
    const int start = row_ptr[node];
    const int cnt   = row_ptr[node + 1] - start;
    const int ocnt  = __shfl_xor(cnt, 32, 64);
    const int mn = min(cnt, ocnt);
    const int mx = max(cnt, ocnt);

    float4 acc0 = make_float4(0.f, 0.f, 0.f, 0.f);
    float4 acc1 = make_float4(0.f, 0.f, 0.f, 0.f);
    int k = 0;
    #pragma unroll 2
    for (; k + 4 <= mn; k += 4) {
        const int j = start + k;
        const int s0 = csr[j], s1 = csr[j + 1], s2 = csr[j + 2], s3 = csr[j + 3];
        const uint32 w0 = zin[(s0 << 5) + l];
        const uint32 w1 = zin[(s1 << 5) + l];
        const uint32 w2 = zin[(s2 << 5) + l];
        const uint32 w3 = zin[(s3 << 5) + l];
        const float4 u0 = unpack4_fp8(w0);
        const float4 u1 = unpack4_fp8(w1);
        const float4 u2 = unpack4_fp8(w2);
        const float4 u3 = unpack4_fp8(w3);
        acc0.x += u0.x + u1.x; acc0.y += u0.y + u1.y;
        acc0.z += u0.z + u1.z; acc0.w += u0.w + u1.w;
        acc1.x += u2.x + u3.x; acc1.y += u2.y + u3.y;
        acc1.z += u2.z + u3.z; acc1.w += u2.w + u3.w;
    }
    for (; k < mx; ++k) {
        const bool valid = k < cnt;
        const int j = valid ? start + k : 0;
        const int s = csr[j];
        const float4 u = unpack4_fp8(zin[(s << 5) + l]);
        if (valid) {
            acc0.x += u.x; acc0.y += u.y; acc0.z += u.z; acc0.w += u.w;
        }
    }
    const float invd = 0.9f / ((float)cnt + 1e-16f);
    const uint2 vv2 = *(const uint2*)&vb[(size_t)node * 64 + 2 * l];
    const uint2 ss2 = *(const uint2*)&skipb[(size_t)node * 64 + 2 * l];
    const float2 va = unpack_bf16_pair(vv2.x);
    const float2 vbp = unpack_bf16_pair(vv2.y);
    const float2 sa = unpack_bf16_pair(ss2.x);
    const float2 sb = unpack_bf16_pair(ss2.y);
    const float4 lb = *(const float4*)&lin_b[4 * l];
    float tx = (acc0.x + acc1.x) * invd + 0.1f * va.x + sa.x + lb.x;
    float ty = (acc0.y + acc1.y) * invd + 0.1f * va.y + sa.y + lb.y;
    float tz = (acc0.z + acc1.z) * invd + 0.1f * vbp.x + sb.x + lb.z;
    float tw = (acc0.w + acc1.w) * invd + 0.1f * vbp.y + sb.y + lb.w;

    float s = tx + ty + tz + tw;
    float q = tx * tx + ty * ty + tz * tz + tw * tw;
    #pragma unroll
    for (int off = 16; off; off >>= 1) {
        s += __shfl_xor(s, off, 64);
        q += __shfl_xor(q, off, 64);
    }
    const float mu   = s * (1.0f / 128.0f);
    const float var  = q * (1.0f / 128.0f) - mu * mu;
    const float rstd = rsqrtf(var + 1e-5f);
    const float4 g = *(const float4*)&ln_g[4 * l];
    const float4 b = *(const float4*)&ln_b[4 * l];
    float4 o;
    o.x = (tx - mu) * rstd * g.x + b.x;
    o.y = (ty - mu) * rstd * g.y + b.y;
    o.z = (tz - mu) * rstd * g.z + b.z;
    o.w = (tw - mu) * rstd * g.w + b.w;
    *(float4*)&out[(size_t)node * DIM + 4 * l] = o;
}

// ---------------------------------------------------------------------------
extern "C" void kernel_launch(void* const* d_in, const int* in_sizes, int n_in,
                              void* d_out, int out_size, void* d_ws, size_t ws_size,
                              hipStream_t stream) {
    const float* x      = (const float*)d_in[0];
    const int*   e      = (const int*)d_in[1];
    const float* lin_w  = (const float*)d_in[2];
    const float* lin_b  = (const float*)d_in[3];
    const float* skip_w = (const float*)d_in[4];
    const float* ln_g   = (const float*)d_in[5];
    const float* ln_b   = (const float*)d_in[6];
    float* out = (float*)d_out;

    const int* e0 = e;
    const int* e1 = e + M_EDGES;

    // workspace layout
    char* ws = (char*)d_ws;
    const size_t hsz = (size_t)N_NODES * DIM * sizeof(ushort);   // 25.6 MB
    const size_t qsz = (size_t)N_NODES * DIM;                    // 12.8 MB
    const size_t psz = (size_t)NB * CAP * sizeof(uint32);        // 8.03 MB
    ushort* vb    = (ushort*)(ws);
    ushort* skipb = (ushort*)(ws + hsz);
    ushort* zA    = (ushort*)(ws + 2 * hsz);
    ushort* zB    = (ushort*)(ws + 2 * hsz + qsz);
    ushort* wt    = (ushort*)(ws + 2 * hsz + 2 * qsz);
    uint32* pairs = (uint32*)(ws + 2 * hsz + 2 * qsz + 65536);
    int* row_ptr  = (int*)(ws + 2 * hsz + 2 * qsz + 65536 + psz);
    int* g_cnt    = row_ptr + (N_NODES + 1);
    int* g_base   = g_cnt + NB;
    int* csr      = g_base + NB + 2;

    // ---- CSR build (bucketed, LDS-atomic) ----
    hipMemsetAsync(g_cnt, 0, NB * sizeof(int), stream);
    partA<<<PA_BLOCKS, 256, 0, stream>>>(e0, e1, g_cnt, pairs);
    bucket_scan<<<1, 256, 0, stream>>>(g_cnt, g_base, row_ptr);
    partB<<<NB, 256, 0, stream>>>(g_cnt, g_base, pairs, row_ptr, csr);

    // ---- weight conversion + fused MFMA GEMM (x converted in-kernel) ----
    convert_w<<<(2 * DIM * DIM) / 256, 256, 0, stream>>>(lin_w, skip_w, wt);
    gemm_mfma<<<(N_NODES + 63) / 64, 256, 0, stream>>>(x, wt, vb, skipb);

    // ---- PPR power iteration (10 steps total) ----
    ppr_init_fp8<<<(N_NODES * DIM / 4) / 256, 256, 0, stream>>>((const uint32*)vb, (uint32*)zA);
    for (int it = 0; it < 8; ++it) {                 // z2..z9
        const ushort* zi = (it & 1) ? zB : zA;
        ushort*       zo = (it & 1) ? zA : zB;
        spmv_fp8<<<N_NODES / 8, 256, 0, stream>>>(row_ptr, csr, (const uint32*)zi,
                                                  (const uint32*)vb, (uint32*)zo);
    }
    // z9 in zA; final step fused with skip+bias+LN
    spmv_final_ln<<<N_NODES / 8, 256, 0, stream>>>(row_ptr, csr, (const uint32*)zA,
                                                   (const uint32*)vb, (const uint32*)skipb,
                                                   lin_b, ln_g, ln_b, out);
}